// Round 1
// baseline (242.901 us; speedup 1.0000x reference)
//
#include <hip/hip_runtime.h>
#include <hip/hip_bf16.h>
#include <math.h>

#define BB 64
#define SS 512
#define DD 256
#define HH 4
// scale = 1/sqrt(256)
#define SCALE 0.0625f

__device__ inline float wave_red_sum(float v) {
#pragma unroll
    for (int off = 32; off > 0; off >>= 1) v += __shfl_xor(v, off, 64);
    return v;
}
__device__ inline float wave_red_max(float v) {
#pragma unroll
    for (int off = 32; off > 0; off >>= 1) v = fmaxf(v, __shfl_xor(v, off, 64));
    return v;
}

// q[h,e] = sum_d seeds[d] * Wq[d,h,e] + bq[h,e]   -- grid 4 x 256, i = h*D+e
__global__ __launch_bounds__(256) void q_kernel(const float* __restrict__ seeds,
                                                const float* __restrict__ Wq,
                                                const float* __restrict__ bq,
                                                float* __restrict__ q) {
    int i = blockIdx.x * 256 + threadIdx.x;  // [0, H*D)
    float acc = bq[i];
#pragma unroll 4
    for (int d = 0; d < DD; ++d) acc += seeds[d] * Wq[(size_t)d * (HH * DD) + i];
    q[i] = acc;
}

// kq[h,d] = sum_e Wk[d,h,e]*q[h,e];  kb[h] = sum_e bk[h,e]*q[h,e]
// grid = H blocks, 256 threads (d)
__global__ __launch_bounds__(256) void kq_kernel(const float* __restrict__ Wk,
                                                 const float* __restrict__ bk,
                                                 const float* __restrict__ q,
                                                 float* __restrict__ kq,
                                                 float* __restrict__ kb) {
    int h = blockIdx.x, d = threadIdx.x;
    __shared__ float ql[DD];
    __shared__ float rbuf[4];
    ql[d] = q[h * DD + d];
    __syncthreads();
    const float4* wrow = reinterpret_cast<const float4*>(Wk + (size_t)d * (HH * DD) + h * DD);
    const float4* q4 = reinterpret_cast<const float4*>(ql);
    float acc = 0.f;
#pragma unroll 8
    for (int e4 = 0; e4 < DD / 4; ++e4) {
        float4 w = wrow[e4];
        float4 qq = q4[e4];
        acc += w.x * qq.x + w.y * qq.y + w.z * qq.z + w.w * qq.w;
    }
    kq[h * DD + d] = acc;
    // kb
    float pb = bk[h * DD + d] * ql[d];
    float t = wave_red_sum(pb);
    int wave = d >> 6, lane = d & 63;
    if (lane == 0) rbuf[wave] = t;
    __syncthreads();
    if (d == 0) kb[h] = rbuf[0] + rbuf[1] + rbuf[2] + rbuf[3];
}

// per-batch: scores -> masked softmax -> xbar[b,h,d] = sum_s attn[h,s]*x[b,s,d]
__global__ __launch_bounds__(256) void attn_xbar_kernel(const float* __restrict__ x,
                                                        const int* __restrict__ mask,
                                                        const float* __restrict__ kq,
                                                        const float* __restrict__ kb,
                                                        float* __restrict__ xbar) {
    __shared__ float kql[HH * DD];  // 4 KB
    __shared__ float sc[HH][SS];    // 8 KB
    __shared__ float kbl[HH];
    int b = blockIdx.x, tid = threadIdx.x;
    for (int i = tid; i < HH * DD; i += 256) kql[i] = kq[i];
    if (tid < HH) kbl[tid] = kb[tid];
    __syncthreads();

    // pass 1: scores, thread handles s = tid and tid+256
    const float4* kq4 = reinterpret_cast<const float4*>(kql);  // [H][64]
#pragma unroll
    for (int rep = 0; rep < 2; ++rep) {
        int s = tid + rep * 256;
        const float4* xrow = reinterpret_cast<const float4*>(x + ((size_t)b * SS + s) * DD);
        float a0 = 0.f, a1 = 0.f, a2 = 0.f, a3 = 0.f;
#pragma unroll 8
        for (int d4 = 0; d4 < DD / 4; ++d4) {
            float4 xv = xrow[d4];
            float4 k0 = kq4[0 * 64 + d4];
            float4 k1 = kq4[1 * 64 + d4];
            float4 k2 = kq4[2 * 64 + d4];
            float4 k3 = kq4[3 * 64 + d4];
            a0 += xv.x * k0.x + xv.y * k0.y + xv.z * k0.z + xv.w * k0.w;
            a1 += xv.x * k1.x + xv.y * k1.y + xv.z * k1.z + xv.w * k1.w;
            a2 += xv.x * k2.x + xv.y * k2.y + xv.z * k2.z + xv.w * k2.w;
            a3 += xv.x * k3.x + xv.y * k3.y + xv.z * k3.z + xv.w * k3.w;
        }
        float madd = (1.0f - (float)mask[b * SS + s]) * -1e9f;
        sc[0][s] = (a0 + kbl[0]) * SCALE + madd;
        sc[1][s] = (a1 + kbl[1]) * SCALE + madd;
        sc[2][s] = (a2 + kbl[2]) * SCALE + madd;
        sc[3][s] = (a3 + kbl[3]) * SCALE + madd;
    }
    __syncthreads();

    // pass 2: softmax; wave w owns head w (512 vals -> 8 per lane)
    int wave = tid >> 6, lane = tid & 63;
    {
        float vals[8];
        float m = -1e30f;
#pragma unroll
        for (int k = 0; k < 8; ++k) {
            vals[k] = sc[wave][lane + 64 * k];
            m = fmaxf(m, vals[k]);
        }
        m = wave_red_max(m);
        float l = 0.f;
#pragma unroll
        for (int k = 0; k < 8; ++k) {
            vals[k] = __expf(vals[k] - m);
            l += vals[k];
        }
        l = wave_red_sum(l);
        float inv = 1.0f / l;
#pragma unroll
        for (int k = 0; k < 8; ++k) sc[wave][lane + 64 * k] = vals[k] * inv;
    }
    __syncthreads();

    // pass 3: xbar, thread owns d = tid, coalesced column pass
    float a0 = 0.f, a1 = 0.f, a2 = 0.f, a3 = 0.f;
    const float* xb = x + (size_t)b * SS * DD + tid;
#pragma unroll 8
    for (int s = 0; s < SS; ++s) {
        float xv = xb[(size_t)s * DD];
        a0 += sc[0][s] * xv;
        a1 += sc[1][s] * xv;
        a2 += sc[2][s] * xv;
        a3 += sc[3][s] * xv;
    }
    float* xo = xbar + (size_t)b * HH * DD;
    xo[0 * DD + tid] = a0;
    xo[1 * DD + tid] = a1;
    xo[2 * DD + tid] = a2;
    xo[3 * DD + tid] = a3;
}

// per-batch: o[h,e] = xbar[b,h,:]·Wv[:,h,e] + bv[h,e];
// h[d] = sum_{h,e} o[h,e]*Wo[h,e,d] + bo[d] + seeds[d]; LN; out[b,d]
__global__ __launch_bounds__(256) void final_kernel(const float* __restrict__ xbar,
                                                    const float* __restrict__ Wv,
                                                    const float* __restrict__ bv,
                                                    const float* __restrict__ Wo,
                                                    const float* __restrict__ bo,
                                                    const float* __restrict__ seeds,
                                                    const float* __restrict__ gamma,
                                                    const float* __restrict__ beta,
                                                    float* __restrict__ out) {
    __shared__ float xb[HH * DD];  // 4 KB
    __shared__ float ol[HH * DD];  // 4 KB
    __shared__ float r1[4], r2[4];
    int b = blockIdx.x, tid = threadIdx.x;
    int wave = tid >> 6, lane = tid & 63;
    for (int i = tid; i < HH * DD; i += 256) xb[i] = xbar[(size_t)b * HH * DD + i];
    __syncthreads();

#pragma unroll
    for (int h = 0; h < HH; ++h) {
        float acc = bv[h * DD + tid];
        const float* wcol = Wv + h * DD + tid;  // Wv[d*1024 + h*256 + e]
#pragma unroll 8
        for (int d = 0; d < DD; ++d) acc += xb[h * DD + d] * wcol[(size_t)d * (HH * DD)];
        ol[h * DD + tid] = acc;
    }
    __syncthreads();

    float acc = bo[tid] + seeds[tid];
    const float* wo = Wo + tid;  // Wo[(h*D+e)*D + d]
#pragma unroll 8
    for (int i = 0; i < HH * DD; ++i) acc += ol[i] * wo[(size_t)i * DD];

    // LayerNorm over the 256 values (one per thread)
    float t = wave_red_sum(acc);
    if (lane == 0) r1[wave] = t;
    __syncthreads();
    float mu = (r1[0] + r1[1] + r1[2] + r1[3]) * (1.0f / DD);
    float dv = acc - mu;
    float t2 = wave_red_sum(dv * dv);
    if (lane == 0) r2[wave] = t2;
    __syncthreads();
    float var = (r2[0] + r2[1] + r2[2] + r2[3]) * (1.0f / DD);
    out[(size_t)b * DD + tid] = dv * rsqrtf(var + 1e-6f) * gamma[tid] + beta[tid];
}

extern "C" void kernel_launch(void* const* d_in, const int* in_sizes, int n_in,
                              void* d_out, int out_size, void* d_ws, size_t ws_size,
                              hipStream_t stream) {
    const float* x = (const float*)d_in[0];
    const int* mask = (const int*)d_in[1];
    const float* seeds = (const float*)d_in[2];
    const float* Wq = (const float*)d_in[3];
    const float* bq = (const float*)d_in[4];
    const float* Wk = (const float*)d_in[5];
    const float* bk = (const float*)d_in[6];
    const float* Wv = (const float*)d_in[7];
    const float* bv = (const float*)d_in[8];
    const float* Wo = (const float*)d_in[9];
    const float* bo = (const float*)d_in[10];
    const float* gamma = (const float*)d_in[11];
    const float* beta = (const float*)d_in[12];
    float* out = (float*)d_out;

    float* ws = (float*)d_ws;
    float* q = ws;             // 1024
    float* kq = ws + 1024;     // 1024
    float* kb = ws + 2048;     // 4
    float* xbar = ws + 2112;   // B*H*D = 65536

    q_kernel<<<4, 256, 0, stream>>>(seeds, Wq, bq, q);
    kq_kernel<<<HH, 256, 0, stream>>>(Wk, bk, q, kq, kb);
    attn_xbar_kernel<<<BB, 256, 0, stream>>>(x, mask, kq, kb, xbar);
    final_kernel<<<BB, 256, 0, stream>>>(xbar, Wv, bv, Wo, bo, seeds, gamma, beta, out);
}

// Round 3
// 150.951 us; speedup vs baseline: 1.6091x; 1.6091x over previous
//
#include <hip/hip_runtime.h>
#include <hip/hip_bf16.h>
#include <math.h>

#define BB 64
#define SS 512
#define DD 256
#define HH 4
#define SCALE 0.0625f  // 1/sqrt(256)

__device__ inline float wave_red_sum(float v) {
#pragma unroll
    for (int off = 32; off > 0; off >>= 1) v += __shfl_xor(v, off, 64);
    return v;
}
__device__ inline float wave_red_max(float v) {
#pragma unroll
    for (int off = 32; off > 0; off >>= 1) v = fmaxf(v, __shfl_xor(v, off, 64));
    return v;
}

// K1: qp[c][i] = sum_{d in chunk c} seeds[d]*Wq[d,i]   (i = h*256+e, 16 chunks of 16 d)
__global__ __launch_bounds__(256) void qp_kernel(const float* __restrict__ seeds,
                                                 const float* __restrict__ Wq,
                                                 float* __restrict__ qp) {
    int c = blockIdx.x, tid = threadIdx.x;
    __shared__ float sl[16];
    if (tid < 16) sl[tid] = seeds[c * 16 + tid];
    __syncthreads();
#pragma unroll
    for (int rep = 0; rep < 4; ++rep) {
        int i = tid + rep * 256;
        float acc = 0.f;
#pragma unroll
        for (int dl = 0; dl < 16; ++dl)
            acc += sl[dl] * Wq[(size_t)(c * 16 + dl) * (HH * DD) + i];
        qp[c * (HH * DD) + i] = acc;
    }
}

// K2: block (h, es): q[h, e-range] = bq + sum_c qp; kqp[es][h][d] = sum_{e in range} Wk[d,h,e]*q[h,e]
//     kbp[es][h] = sum_{e in range} bk[h,e]*q[h,e]
__global__ __launch_bounds__(256) void kq_kernel(const float* __restrict__ Wk,
                                                 const float* __restrict__ bk,
                                                 const float* __restrict__ bq,
                                                 const float* __restrict__ qp,
                                                 float* __restrict__ kqp,
                                                 float* __restrict__ kbp) {
    int h = blockIdx.x >> 2, es = blockIdx.x & 3;
    int d = threadIdx.x;
    __shared__ float ql[64];
    __shared__ float bkq[64];
    int e0 = es * 64;
    if (d < 64) {
        int i = h * DD + e0 + d;
        float qv = bq[i];
#pragma unroll
        for (int c = 0; c < 16; ++c) qv += qp[c * (HH * DD) + i];
        ql[d] = qv;
        bkq[d] = bk[i] * qv;
    }
    __syncthreads();
    const float4* w4 = reinterpret_cast<const float4*>(Wk + (size_t)d * (HH * DD) + h * DD + e0);
    const float4* q4 = reinterpret_cast<const float4*>(ql);
    float acc = 0.f;
#pragma unroll
    for (int e4 = 0; e4 < 16; ++e4) {
        float4 w = w4[e4], qq = q4[e4];
        acc += w.x * qq.x + w.y * qq.y + w.z * qq.z + w.w * qq.w;
    }
    kqp[(es * HH + h) * DD + d] = acc;
    if (d < 64) {
        float v = wave_red_sum(bkq[d]);
        if (d == 0) kbp[es * HH + h] = v;
    }
}

// K3: block (b, st): scores[b,h,s] for s in 128-row tile; thread = (half, s_local)
__global__ __launch_bounds__(256) void scores_kernel(const float* __restrict__ x,
                                                     const int* __restrict__ mask,
                                                     const float* __restrict__ kqp,
                                                     const float* __restrict__ kbp,
                                                     float* __restrict__ scores) {
    int b = blockIdx.x >> 2, st = blockIdx.x & 3;
    int tid = threadIdx.x;
    __shared__ float kql[HH][DD];
    __shared__ float kbl[HH];
    __shared__ float part[2][HH][128];
    for (int i = tid; i < HH * DD; i += 256) {
        int h = i >> 8, d = i & 255;
        float v = 0.f;
#pragma unroll
        for (int es = 0; es < 4; ++es) v += kqp[(es * HH + h) * DD + d];
        kql[h][d] = v;
    }
    if (tid < HH) {
        float v = 0.f;
#pragma unroll
        for (int es = 0; es < 4; ++es) v += kbp[es * HH + tid];
        kbl[tid] = v;
    }
    __syncthreads();

    int sl = tid & 127, half = tid >> 7;
    int s = st * 128 + sl;
    const float4* xr = reinterpret_cast<const float4*>(x + ((size_t)b * SS + s) * DD + half * 128);
    const float4* k0 = reinterpret_cast<const float4*>(&kql[0][half * 128]);
    const float4* k1 = reinterpret_cast<const float4*>(&kql[1][half * 128]);
    const float4* k2 = reinterpret_cast<const float4*>(&kql[2][half * 128]);
    const float4* k3 = reinterpret_cast<const float4*>(&kql[3][half * 128]);
    float a0 = 0.f, a1 = 0.f, a2 = 0.f, a3 = 0.f;
#pragma unroll 8
    for (int d4 = 0; d4 < 32; ++d4) {
        float4 xv = xr[d4];
        float4 w0 = k0[d4], w1 = k1[d4], w2 = k2[d4], w3 = k3[d4];
        a0 += xv.x * w0.x + xv.y * w0.y + xv.z * w0.z + xv.w * w0.w;
        a1 += xv.x * w1.x + xv.y * w1.y + xv.z * w1.z + xv.w * w1.w;
        a2 += xv.x * w2.x + xv.y * w2.y + xv.z * w2.z + xv.w * w2.w;
        a3 += xv.x * w3.x + xv.y * w3.y + xv.z * w3.z + xv.w * w3.w;
    }
    part[half][0][sl] = a0;
    part[half][1][sl] = a1;
    part[half][2][sl] = a2;
    part[half][3][sl] = a3;
    __syncthreads();
    if (half == 0) {
        float madd = (1.0f - (float)mask[b * SS + s]) * -1e9f;
#pragma unroll
        for (int h = 0; h < HH; ++h) {
            float v = part[0][h][sl] + part[1][h][sl] + kbl[h];
            scores[((size_t)(b * HH + h)) * SS + s] = v * SCALE + madd;
        }
    }
}

// K4: block (b, st): softmax over full S per head (wave=head), then partial
//     xbarp[b][st][h][d] = sum_{s in tile} attn[h,s]*x[b,s,d]
__global__ __launch_bounds__(256) void xbar_kernel(const float* __restrict__ x,
                                                   const float* __restrict__ scores,
                                                   float* __restrict__ xbarp) {
    int b = blockIdx.x >> 2, st = blockIdx.x & 3;
    int tid = threadIdx.x, wave = tid >> 6, lane = tid & 63;
    __shared__ float at[HH][SS];
    {
        float vals[8];
        float m = -1e30f;
        const float* sr = scores + ((size_t)(b * HH + wave)) * SS;
#pragma unroll
        for (int k = 0; k < 8; ++k) {
            vals[k] = sr[lane + 64 * k];
            m = fmaxf(m, vals[k]);
        }
        m = wave_red_max(m);
        float l = 0.f;
#pragma unroll
        for (int k = 0; k < 8; ++k) {
            vals[k] = __expf(vals[k] - m);
            l += vals[k];
        }
        l = wave_red_sum(l);
        float inv = 1.0f / l;
#pragma unroll
        for (int k = 0; k < 8; ++k) at[wave][lane + 64 * k] = vals[k] * inv;
    }
    __syncthreads();

    float a0 = 0.f, a1 = 0.f, a2 = 0.f, a3 = 0.f;
    const float* xb = x + ((size_t)b * SS + st * 128) * DD + tid;
#pragma unroll 4
    for (int s = 0; s < 128; ++s) {
        float xv = xb[(size_t)s * DD];
        int sg = st * 128 + s;
        a0 += at[0][sg] * xv;
        a1 += at[1][sg] * xv;
        a2 += at[2][sg] * xv;
        a3 += at[3][sg] * xv;
    }
    float* xo = xbarp + ((size_t)(b * 4 + st)) * (HH * DD);
    xo[0 * DD + tid] = a0;
    xo[1 * DD + tid] = a1;
    xo[2 * DD + tid] = a2;
    xo[3 * DD + tid] = a3;
}

// K5: block (b, h): xbar = sum_st xbarp; ol[e] = bv + xbar·Wv[:,h,e];
//     wop[b][h][d] = sum_e ol[e]*Wo[h,e,d]
__global__ __launch_bounds__(256) void ovwo_kernel(const float* __restrict__ xbarp,
                                                   const float* __restrict__ Wv,
                                                   const float* __restrict__ bv,
                                                   const float* __restrict__ Wo,
                                                   float* __restrict__ wop) {
    int b = blockIdx.x >> 2, h = blockIdx.x & 3;
    int tid = threadIdx.x;
    __shared__ float xl[DD];
    __shared__ float ol[DD];
    float v = 0.f;
#pragma unroll
    for (int st = 0; st < 4; ++st) v += xbarp[((size_t)(b * 4 + st)) * (HH * DD) + h * DD + tid];
    xl[tid] = v;
    __syncthreads();
    float acc = bv[h * DD + tid];
    const float* wv = Wv + h * DD + tid;
#pragma unroll 8
    for (int d = 0; d < DD; ++d) acc += xl[d] * wv[(size_t)d * (HH * DD)];
    ol[tid] = acc;
    __syncthreads();
    float acc2 = 0.f;
    const float* wo = Wo + (size_t)(h * DD) * DD + tid;
#pragma unroll 8
    for (int e = 0; e < DD; ++e) acc2 += ol[e] * wo[(size_t)e * DD];
    wop[((size_t)(b * HH + h)) * DD + tid] = acc2;
}

// K6: block b: h_pre = sum_h wop + bo + seeds; LayerNorm; out[b,:]
__global__ __launch_bounds__(256) void ln_kernel(const float* __restrict__ wop,
                                                 const float* __restrict__ bo,
                                                 const float* __restrict__ seeds,
                                                 const float* __restrict__ gamma,
                                                 const float* __restrict__ beta,
                                                 float* __restrict__ out) {
    __shared__ float r1[4], r2[4];
    int b = blockIdx.x, tid = threadIdx.x;
    int wave = tid >> 6, lane = tid & 63;
    float acc = bo[tid] + seeds[tid];
#pragma unroll
    for (int h = 0; h < HH; ++h) acc += wop[((size_t)(b * HH + h)) * DD + tid];

    float t = wave_red_sum(acc);
    if (lane == 0) r1[wave] = t;
    __syncthreads();
    float mu = (r1[0] + r1[1] + r1[2] + r1[3]) * (1.0f / DD);
    float dv = acc - mu;
    float t2 = wave_red_sum(dv * dv);
    if (lane == 0) r2[wave] = t2;
    __syncthreads();
    float var = (r2[0] + r2[1] + r2[2] + r2[3]) * (1.0f / DD);
    out[(size_t)b * DD + tid] = dv * rsqrtf(var + 1e-6f) * gamma[tid] + beta[tid];
}

extern "C" void kernel_launch(void* const* d_in, const int* in_sizes, int n_in,
                              void* d_out, int out_size, void* d_ws, size_t ws_size,
                              hipStream_t stream) {
    const float* x = (const float*)d_in[0];
    const int* mask = (const int*)d_in[1];
    const float* seeds = (const float*)d_in[2];
    const float* Wq = (const float*)d_in[3];
    const float* bq = (const float*)d_in[4];
    const float* Wk = (const float*)d_in[5];
    const float* bk = (const float*)d_in[6];
    const float* Wv = (const float*)d_in[7];
    const float* bv = (const float*)d_in[8];
    const float* Wo = (const float*)d_in[9];
    const float* bo = (const float*)d_in[10];
    const float* gamma = (const float*)d_in[11];
    const float* beta = (const float*)d_in[12];
    float* out = (float*)d_out;

    float* ws = (float*)d_ws;
    float* qp = ws;                       // 16*1024 = 16384
    float* kqp = qp + 16384;              // 4*4*256 = 4096
    float* kbp = kqp + 4096;              // 16
    float* scores = kbp + 16;             // 64*4*512 = 131072
    float* xbarp = scores + 131072;       // 64*4*4*256 = 262144
    float* wop = xbarp + 262144;          // 64*4*256 = 65536

    qp_kernel<<<16, 256, 0, stream>>>(seeds, Wq, qp);
    kq_kernel<<<16, 256, 0, stream>>>(Wk, bk, bq, qp, kqp, kbp);
    scores_kernel<<<BB * 4, 256, 0, stream>>>(x, mask, kqp, kbp, scores);
    xbar_kernel<<<BB * 4, 256, 0, stream>>>(x, scores, xbarp);
    ovwo_kernel<<<BB * HH, 256, 0, stream>>>(xbarp, Wv, bv, Wo, wop);
    ln_kernel<<<BB, 256, 0, stream>>>(wop, bo, seeds, gamma, beta, out);
}

// Round 7
// 140.657 us; speedup vs baseline: 1.7269x; 1.0732x over previous
//
#include <hip/hip_runtime.h>
#include <hip/hip_bf16.h>
#include <math.h>

#define BB 64
#define SS 512
#define DD 256
#define HH 4
#define SCALE 0.0625f  // 1/sqrt(256)
#define PAD 261        // row stride >= 256; odd (261%32=5) -> per-lane row-stride access is 2-way (free)

__device__ inline float wave_red_sum(float v) {
#pragma unroll
    for (int off = 32; off > 0; off >>= 1) v += __shfl_xor(v, off, 64);
    return v;
}
__device__ inline float wave_red_max(float v) {
#pragma unroll
    for (int off = 32; off > 0; off >>= 1) v = fmaxf(v, __shfl_xor(v, off, 64));
    return v;
}

// K1: qp[c][i] = sum_{d in chunk c} seeds[d]*Wq[d,i]   (i = h*256+e, 16 chunks of 16 d)
__global__ __launch_bounds__(256) void qp_kernel(const float* __restrict__ seeds,
                                                 const float* __restrict__ Wq,
                                                 float* __restrict__ qp) {
    int c = blockIdx.x, tid = threadIdx.x;
    __shared__ float sl[16];
    if (tid < 16) sl[tid] = seeds[c * 16 + tid];
    __syncthreads();
#pragma unroll
    for (int rep = 0; rep < 4; ++rep) {
        int i = tid + rep * 256;
        float acc = 0.f;
#pragma unroll
        for (int dl = 0; dl < 16; ++dl)
            acc += sl[dl] * Wq[(size_t)(c * 16 + dl) * (HH * DD) + i];
        qp[c * (HH * DD) + i] = acc;
    }
}

// K2: block (h, ds): final kq[h][d] for d in [ds*64, +64), and kb[h] (redundant write)
__global__ __launch_bounds__(256) void kqf_kernel(const float* __restrict__ Wk,
                                                  const float* __restrict__ bk,
                                                  const float* __restrict__ bq,
                                                  const float* __restrict__ qp,
                                                  float* __restrict__ kqf,
                                                  float* __restrict__ kbg) {
    int h = blockIdx.x >> 2, ds = blockIdx.x & 3;
    int tid = threadIdx.x, w = tid >> 6, lane = tid & 63;
    __shared__ float ql[DD];
    __shared__ float red[4][64];
    __shared__ float rb[4];
    // full q[h][:]
    float qv = bq[h * DD + tid];
#pragma unroll
    for (int c = 0; c < 16; ++c) qv += qp[c * (HH * DD) + h * DD + tid];
    ql[tid] = qv;
    float bkv = bk[h * DD + tid] * qv;
    float t1 = wave_red_sum(bkv);
    if (lane == 0) rb[w] = t1;
    __syncthreads();
    if (tid == 0) kbg[h] = rb[0] + rb[1] + rb[2] + rb[3];
    // kq partial over e-quarter
    int dl = tid & 63, ec = tid >> 6;
    int d = ds * 64 + dl;
    const float4* wrow = reinterpret_cast<const float4*>(Wk + (size_t)d * (HH * DD) + h * DD + ec * 64);
    const float4* qq4 = reinterpret_cast<const float4*>(&ql[ec * 64]);
    float acc = 0.f;
#pragma unroll
    for (int e4 = 0; e4 < 16; ++e4) {
        float4 wv = wrow[e4], qq = qq4[e4];
        acc += wv.x * qq.x + wv.y * qq.y + wv.z * qq.z + wv.w * qq.w;
    }
    red[ec][dl] = acc;
    __syncthreads();
    if (tid < 64) kqf[h * DD + ds * 64 + tid] = red[0][tid] + red[1][tid] + red[2][tid] + red[3][tid];
}

// K3: flash-style fused scores+softmax+weighted-sum. block = (b, st) of 64 rows.
// Writes per-tile m, l, and xp[tile][h][d] = sum_s exp(score-m)*x[s,d]
__global__ __launch_bounds__(256) void flash_kernel(const float* __restrict__ x,
                                                    const int* __restrict__ mask,
                                                    const float* __restrict__ kqg,
                                                    const float* __restrict__ kbg,
                                                    float* __restrict__ xp,
                                                    float* __restrict__ mt,
                                                    float* __restrict__ lt) {
    int b = blockIdx.x >> 3, st = blockIdx.x & 7;
    int tid = threadIdx.x, w = tid >> 6, lane = tid & 63;
    __shared__ float xt[64][PAD];
    __shared__ __align__(16) float part[4][2][64];  // later aliased as sc[4][64]
    float* sc = &part[0][0][0];

    // P1: perfectly-coalesced float4 load of the 64x256 tile -> LDS
    const float4* xg = reinterpret_cast<const float4*>(x + ((size_t)b * SS + st * 64) * DD);
#pragma unroll
    for (int c = 0; c < 16; ++c) {
        int f = c * 256 + tid;
        float4 v = xg[f];
        int row = f >> 6, col = (f & 63) * 4;
        xt[row][col + 0] = v.x;
        xt[row][col + 1] = v.y;
        xt[row][col + 2] = v.z;
        xt[row][col + 3] = v.w;
    }
    __syncthreads();

    // P2: dots. wave w handles heads {2*(w>>1), +1}, k-half (w&1); lane = s.
    int s = lane;
    int hp = w >> 1, kk = w & 1;
    int off = __builtin_amdgcn_readfirstlane(hp * 2 * DD + kk * 128);
    const float* kA = kqg + off;        // head 2*hp, this k-half
    const float* kB = kqg + off + DD;   // head 2*hp+1
    const float* xrow = &xt[s][kk * 128];
    float a0 = 0.f, a1 = 0.f;
#pragma unroll 16
    for (int k = 0; k < 128; ++k) {
        float xv = xrow[k];
        a0 = fmaf(xv, kA[k], a0);
        a1 = fmaf(xv, kB[k], a1);
    }
    part[w][0][s] = a0;
    part[w][1][s] = a1;
    __syncthreads();

    // softmax: wave w = head h, lane = s
    int h = w;
    float v = part[2 * (h >> 1)][h & 1][s] + part[2 * (h >> 1) + 1][h & 1][s];
    float score = (v + kbg[h]) * SCALE + (1.f - (float)mask[b * SS + st * 64 + s]) * -1e9f;
    float m = wave_red_max(score);
    float p = __expf(score - m);
    float l = wave_red_sum(p);
    __syncthreads();  // all part reads complete before aliased write
    sc[h * 64 + s] = p;
    if (lane == 0) {
        mt[blockIdx.x * 4 + h] = m;
        lt[blockIdx.x * 4 + h] = l;
    }
    __syncthreads();

    // P3: thread d = tid: o_h[d] = sum_s p[h][s] * xt[s][d]
    float o0 = 0.f, o1 = 0.f, o2 = 0.f, o3 = 0.f;
#pragma unroll 4
    for (int sb = 0; sb < 16; ++sb) {
        float4 p0 = *reinterpret_cast<const float4*>(&sc[0 * 64 + 4 * sb]);
        float4 p1 = *reinterpret_cast<const float4*>(&sc[1 * 64 + 4 * sb]);
        float4 p2 = *reinterpret_cast<const float4*>(&sc[2 * 64 + 4 * sb]);
        float4 p3 = *reinterpret_cast<const float4*>(&sc[3 * 64 + 4 * sb]);
#pragma unroll
        for (int j = 0; j < 4; ++j) {
            float xv = xt[4 * sb + j][tid];
            float pj0 = (j == 0) ? p0.x : (j == 1) ? p0.y : (j == 2) ? p0.z : p0.w;
            float pj1 = (j == 0) ? p1.x : (j == 1) ? p1.y : (j == 2) ? p1.z : p1.w;
            float pj2 = (j == 0) ? p2.x : (j == 1) ? p2.y : (j == 2) ? p2.z : p2.w;
            float pj3 = (j == 0) ? p3.x : (j == 1) ? p3.y : (j == 2) ? p3.z : p3.w;
            o0 = fmaf(pj0, xv, o0);
            o1 = fmaf(pj1, xv, o1);
            o2 = fmaf(pj2, xv, o2);
            o3 = fmaf(pj3, xv, o3);
        }
    }
    float* xpo = xp + (size_t)blockIdx.x * 4 * DD;
    xpo[0 * DD + tid] = o0;
    xpo[1 * DD + tid] = o1;
    xpo[2 * DD + tid] = o2;
    xpo[3 * DD + tid] = o3;
}

// K4: block (b,h): combine tiles -> xbar; ol = bv + xbar·Wv; wop = ol·Wo
__global__ __launch_bounds__(256) void ovwo_kernel(const float* __restrict__ xp,
                                                   const float* __restrict__ mt,
                                                   const float* __restrict__ lt,
                                                   const float* __restrict__ Wv,
                                                   const float* __restrict__ bv,
                                                   const float* __restrict__ Wo,
                                                   float* __restrict__ wop) {
    int b = blockIdx.x >> 2, h = blockIdx.x & 3;
    int tid = threadIdx.x;
    __shared__ float xl[DD];
    __shared__ float ol[DD];
    float M = -3.0e38f;
#pragma unroll
    for (int t = 0; t < 8; ++t) M = fmaxf(M, mt[(b * 8 + t) * 4 + h]);
    float L = 0.f;
    float co[8];
#pragma unroll
    for (int t = 0; t < 8; ++t) {
        co[t] = __expf(mt[(b * 8 + t) * 4 + h] - M);
        L += lt[(b * 8 + t) * 4 + h] * co[t];
    }
    float invL = 1.0f / L;
    float xb = 0.f;
#pragma unroll
    for (int t = 0; t < 8; ++t) xb += co[t] * xp[((size_t)(b * 8 + t) * 4 + h) * DD + tid];
    xl[tid] = xb * invL;
    __syncthreads();
    float acc = bv[h * DD + tid];
    const float* wv = Wv + h * DD + tid;
#pragma unroll 8
    for (int d = 0; d < DD; ++d) acc += xl[d] * wv[(size_t)d * (HH * DD)];
    ol[tid] = acc;
    __syncthreads();
    float a2 = 0.f;
    const float* wo = Wo + (size_t)(h * DD) * DD + tid;
#pragma unroll 8
    for (int e = 0; e < DD; ++e) a2 += ol[e] * wo[(size_t)e * DD];
    wop[((size_t)(b * HH + h)) * DD + tid] = a2;
}

// K5: block b: h_pre = sum_h wop + bo + seeds; LayerNorm; out[b,:]
__global__ __launch_bounds__(256) void ln_kernel(const float* __restrict__ wop,
                                                 const float* __restrict__ bo,
                                                 const float* __restrict__ seeds,
                                                 const float* __restrict__ gamma,
                                                 const float* __restrict__ beta,
                                                 float* __restrict__ out) {
    __shared__ float r1[4], r2[4];
    int b = blockIdx.x, tid = threadIdx.x;
    int w = tid >> 6, lane = tid & 63;
    float acc = bo[tid] + seeds[tid];
#pragma unroll
    for (int h = 0; h < HH; ++h) acc += wop[((size_t)(b * HH + h)) * DD + tid];

    float t = wave_red_sum(acc);
    if (lane == 0) r1[w] = t;
    __syncthreads();
    float mu = (r1[0] + r1[1] + r1[2] + r1[3]) * (1.0f / DD);
    float dv = acc - mu;
    float t2 = wave_red_sum(dv * dv);
    if (lane == 0) r2[w] = t2;
    __syncthreads();
    float var = (r2[0] + r2[1] + r2[2] + r2[3]) * (1.0f / DD);
    out[(size_t)b * DD + tid] = dv * rsqrtf(var + 1e-6f) * gamma[tid] + beta[tid];
}

extern "C" void kernel_launch(void* const* d_in, const int* in_sizes, int n_in,
                              void* d_out, int out_size, void* d_ws, size_t ws_size,
                              hipStream_t stream) {
    const float* x = (const float*)d_in[0];
    const int* mask = (const int*)d_in[1];
    const float* seeds = (const float*)d_in[2];
    const float* Wq = (const float*)d_in[3];
    const float* bq = (const float*)d_in[4];
    const float* Wk = (const float*)d_in[5];
    const float* bk = (const float*)d_in[6];
    const float* Wv = (const float*)d_in[7];
    const float* bv = (const float*)d_in[8];
    const float* Wo = (const float*)d_in[9];
    const float* bo = (const float*)d_in[10];
    const float* gamma = (const float*)d_in[11];
    const float* beta = (const float*)d_in[12];
    float* out = (float*)d_out;

    float* ws = (float*)d_ws;
    float* qp  = ws;              // 16*1024        = 16384
    float* kqf = ws + 16384;      // 4*256          = 1024
    float* kbg = ws + 17408;      // 4 (+pad 12)
    float* mt  = ws + 17424;      // 512*4          = 2048
    float* lt  = ws + 19472;      // 512*4          = 2048
    float* xp  = ws + 21520;      // 512*4*256      = 524288
    float* wop = ws + 545808;     // 64*4*256       = 65536

    qp_kernel<<<16, 256, 0, stream>>>(seeds, Wq, qp);
    kqf_kernel<<<16, 256, 0, stream>>>(Wk, bk, bq, qp, kqf, kbg);
    flash_kernel<<<BB * 8, 256, 0, stream>>>(x, mask, kqf, kbg, xp, mt, lt);
    ovwo_kernel<<<BB * HH, 256, 0, stream>>>(xp, mt, lt, Wv, bv, Wo, wop);
    ln_kernel<<<BB, 256, 0, stream>>>(wop, bo, seeds, gamma, beta, out);
}